// Round 10
// baseline (230.059 us; speedup 1.0000x reference)
//
#include <hip/hip_runtime.h>
#include <hip/hip_fp16.h>

#define NB 32
#define NN 1024

typedef _Float16 h2 __attribute__((ext_vector_type(2)));
typedef _Float16 h8 __attribute__((ext_vector_type(8)));

// ---------------- ws layout (floats unless noted) ----------------
static const size_t F_D     = 0;        // 32768  : rsqrt degree [B,N]
static const size_t F_STATS = 32768;    // 16384  : 8 x {sum[1024], sumsq[1024]}
static const size_t F_XW1   = 49152;    // 131072 : x @ W1  [B,N,4]
static constexpr size_t F_Y[8] = {180224, 311296, 376832, 507904,
                                  573440, 704512, 770048, 901120};
static const size_t AH_BYTE_OFF  = 3866624;                 // fp16 adj(diag=1), 64MB
static const size_t WS_NEED_HALF = AH_BYTE_OFF + (size_t)NB*NN*NN*2;

__device__ __forceinline__ float fdot2f(h2 a, h2 b, float c) {
#if __has_builtin(__builtin_amdgcn_fdot2)
    return __builtin_amdgcn_fdot2(a, b, c, false);
#else
    return c + (float)a[0]*(float)b[0] + (float)a[1]*(float)b[1];
#endif
}

// ------------------------------------------------------------------
// K0: degree + write fp16 ah(diag=1) + XW1 precompute + stats zero
__global__ __launch_bounds__(256)
void k0_prep(const float* __restrict__ adj, const float* __restrict__ x,
             const float* __restrict__ W1, float* __restrict__ dd,
             float* __restrict__ xw1, float* __restrict__ stats,
             __half* __restrict__ ahw)
{
    const int tid = threadIdx.x;
    const int bx  = blockIdx.x;
    if (bx < 8192) {
        const int lane = tid & 63, wid = tid >> 6;
        const int row = bx * 4 + wid;          // b*1024+n
        const int n = row & (NN - 1);
        const float4* arow = (const float4*)(adj + (size_t)row * NN);
        uint2* hrow = (uint2*)(ahw + (size_t)row * NN);
        float s = 0.f;
        #pragma unroll
        for (int it = 0; it < 4; ++it) {
            const int idx = lane + it * 64;
            float4 v = arow[idx];
            const int k0 = idx * 4;
            v.x = (k0 + 0 == n) ? 1.f : v.x;
            v.y = (k0 + 1 == n) ? 1.f : v.y;
            v.z = (k0 + 2 == n) ? 1.f : v.z;
            v.w = (k0 + 3 == n) ? 1.f : v.w;
            s += v.x + v.y + v.z + v.w;
            if (ahw) {
                __half2 h01 = __floats2half2_rn(v.x, v.y);
                __half2 h23 = __floats2half2_rn(v.z, v.w);
                uint2 u;
                u.x = *(unsigned*)&h01; u.y = *(unsigned*)&h23;
                hrow[idx] = u;
            }
        }
        #pragma unroll
        for (int m = 1; m < 64; m <<= 1) s += __shfl_xor(s, m);
        if (lane == 0) dd[row] = rsqrtf(fmaxf(s, 1.f));
    } else if (bx < 8320) {
        const int id = (bx - 8192) * 256 + tid;   // b*1024+k
        const float4* xr = (const float4*)(x + (size_t)id * 32);
        float in[32];
        #pragma unroll
        for (int i = 0; i < 8; ++i) {
            float4 v = xr[i];
            in[4*i]=v.x; in[4*i+1]=v.y; in[4*i+2]=v.z; in[4*i+3]=v.w;
        }
        float o[4] = {0.f,0.f,0.f,0.f};
        #pragma unroll
        for (int i = 0; i < 32; ++i)
            #pragma unroll
            for (int c = 0; c < 4; ++c) o[c] += in[i] * W1[i*4+c];
        *(float4*)(xw1 + (size_t)id * 4) = make_float4(o[0],o[1],o[2],o[3]);
    } else {
        const int id = (bx - 8320) * 256 + tid;   // < 16384
        stats[id] = 0.f;
    }
}

// ------------------------------------------------------------------
// Stage one 512-half chunk of this wave's 4 rows into its own LDS region.
// Linear dest (wave-uniform base + lane*16 implicit); source is lane-
// contiguous 1KB per load -> fully coalesced. 4 loads/chunk/wave.
__device__ __forceinline__ void stage_chunk32(const __half* __restrict__ ah,
        int rowbase, int wid, int lane, int ck, char* sbase)
{
    #pragma unroll
    for (int i = 0; i < 4; ++i) {
        char* dst = sbase + (ck << 15) + (wid << 12) + (i << 10);
        const char* g = (const char*)ah +
            (((size_t)(rowbase + (wid << 2) + i)) << 11) + (ck << 10) + (lane << 4);
#if __has_builtin(__builtin_amdgcn_global_load_lds)
        __builtin_amdgcn_global_load_lds(
            (const __attribute__((address_space(1))) void*)g,
            (__attribute__((address_space(3))) void*)dst,
            16, 0, 0);
#else
        *(float4*)(dst + lane * 16) = *(const float4*)g;
#endif
    }
}

// ------------------------------------------------------------------
// Pass kernel: Y = relu(Anorm @ XW + b), Anorm = d[r]*ah[r][k]*d[k].
// Grid 1024: b = bid>>5, tile = (bid&31)*32. 8 waves x 4 rows each.
// Structure: stage BOTH chunks up front -> prologue (hides stage latency)
// -> lgkmcnt(0) + raw s_barrier (XW published; stage loads stay in flight)
// -> vmcnt(4), compute ck0 -> vmcnt(0), compute ck1. No mid-loop drains,
// no buffer reuse, no full __syncthreads vmcnt-drain.
// A-read: all 64 lanes read ONE row, lane-contiguous 16B -> conflict-free.
// XPc[c][k] per-channel linear: lane stride 16B -> conflict-free + aligned.
template<int CIN1, int CIN2, int COUT>
__global__ __launch_bounds__(512, 2)
void pass_half(const __half* __restrict__ ah, const float* __restrict__ dd,
               const float* __restrict__ xw1,
               const float* __restrict__ src1, const float* __restrict__ st1,
               const float* __restrict__ src2, const float* __restrict__ st2,
               const float* __restrict__ W, const float* __restrict__ bias,
               float* __restrict__ Y, float* __restrict__ stout)
{
    __shared__ char sA[65536];                 // 2 chunks x 32 rows x 1KB
    __shared__ _Float16 XPc[COUT][NN];         // per-channel XW*dk
    const int tid = threadIdx.x, lane = tid & 63, wid = tid >> 6;
    const int b = blockIdx.x >> 5;
    const int tile = (blockIdx.x & 31) << 5;
    const int rowbase = b * NN + tile;

    // issue ALL staging first (8 loads/wave in flight)
    stage_chunk32(ah, rowbase, wid, lane, 0, sA);
    stage_chunk32(ah, rowbase, wid, lane, 1, sA);

    // ---- prologue: build fp16 XW (d[k] folded) — hides stage latency ----
    #pragma unroll
    for (int kk = 0; kk < 2; ++kk) {
        const int k = tid + kk * 512;
        float xw[COUT];
        if constexpr (CIN1 == 0) {
            const float4 v = *(const float4*)(xw1 + ((size_t)b*NN + k) * 4);
            xw[0]=v.x; xw[1]=v.y; xw[2]=v.z; xw[3]=v.w;
        } else {
            float in[CIN1 + CIN2];
            {
                const float cnt = 1.f / (32.f * CIN1);
                const float m  = st1[k] * cnt;
                const float ms = st1[NN + k] * cnt;
                const float iv = rsqrtf(ms - m*m + 1e-5f);
                const float4 v = *(const float4*)(src1 + ((size_t)b*NN + k) * CIN1);
                in[0]=(v.x-m)*iv; in[1]=(v.y-m)*iv; in[2]=(v.z-m)*iv; in[3]=(v.w-m)*iv;
            }
            if constexpr (CIN2 > 0) {
                const float cnt = 1.f / (32.f * CIN2);
                const float m  = st2[k] * cnt;
                const float ms = st2[NN + k] * cnt;
                const float iv = rsqrtf(ms - m*m + 1e-5f);
                const float2 v = *(const float2*)(src2 + ((size_t)b*NN + k) * CIN2);
                in[CIN1+0]=(v.x-m)*iv; in[CIN1+1]=(v.y-m)*iv;
            }
            #pragma unroll
            for (int c = 0; c < COUT; ++c) {
                float s = 0.f;
                #pragma unroll
                for (int i = 0; i < CIN1+CIN2; ++i) s += in[i]*W[i*COUT+c];
                xw[c] = s;
            }
        }
        const float dk = dd[b*NN + k];
        #pragma unroll
        for (int c = 0; c < COUT; ++c)
            XPc[c][k] = (_Float16)(xw[c]*dk);
    }

    // publish XPc without draining the stage loads (raw barrier, no vmcnt0)
    asm volatile("s_waitcnt lgkmcnt(0)" ::: "memory");
    __builtin_amdgcn_s_barrier();

    float acc[4][COUT];
    #pragma unroll
    for (int j = 0; j < 4; ++j)
        #pragma unroll
        for (int c = 0; c < COUT; ++c) acc[j][c] = 0.f;

    #pragma unroll
    for (int ck = 0; ck < 2; ++ck) {
        if (ck == 0) asm volatile("s_waitcnt vmcnt(4)" ::: "memory");
        else         asm volatile("s_waitcnt vmcnt(0)" ::: "memory");
        h8 xt[COUT];
        #pragma unroll
        for (int c = 0; c < COUT; ++c)
            xt[c] = *(const h8*)&XPc[c][(ck << 9) + (lane << 3)];
        #pragma unroll
        for (int j = 0; j < 4; ++j) {
            const h8 av = *(const h8*)(sA + (ck << 15) + (wid << 12) +
                                       (j << 10) + (lane << 4));
            const h2* a2 = (const h2*)&av;
            #pragma unroll
            for (int c = 0; c < COUT; ++c) {
                const h2* x2 = (const h2*)&xt[c];
                float s = acc[j][c];
                #pragma unroll
                for (int p = 0; p < 4; ++p)
                    s = fdot2f(a2[p], x2[p], s);
                acc[j][c] = s;
            }
        }
    }

    // ---- 64-lane reduce + epilogue ----
    #pragma unroll
    for (int j = 0; j < 4; ++j)
        #pragma unroll
        for (int c = 0; c < COUT; ++c) {
            float v = acc[j][c];
            v += __shfl_xor(v, 1);  v += __shfl_xor(v, 2);
            v += __shfl_xor(v, 4);  v += __shfl_xor(v, 8);
            v += __shfl_xor(v, 16); v += __shfl_xor(v, 32);
            acc[j][c] = v;
        }
    if (lane == 0) {
        #pragma unroll
        for (int j = 0; j < 4; ++j) {
            const int n = tile + (wid << 2) + j;
            const float dn = dd[b*NN + n];
            float s = 0.f, q2 = 0.f;
            float y[COUT];
            #pragma unroll
            for (int c = 0; c < COUT; ++c) {
                float t = acc[j][c] * dn + bias[c];
                t = fmaxf(t, 0.f);
                y[c] = t; s += t; q2 += t*t;
            }
            if constexpr (COUT == 4)
                *(float4*)(Y + ((size_t)(b*NN + n))*4) = make_float4(y[0],y[1],y[2],y[3]);
            else
                *(float2*)(Y + ((size_t)(b*NN + n))*2) = make_float2(y[0],y[1]);
            atomicAdd(stout + n, s);
            atomicAdd(stout + NN + n, q2);
        }
    }
}

// ------------------------------------------------------------------
// Fallback fp32 pass (no ah): direct adj reads (R2-proven path).
template<int CIN1, int CIN2, int COUT>
__global__ __launch_bounds__(512)
void pass_f32(const float* __restrict__ adj, const float* __restrict__ dd,
              const float* __restrict__ xw1,
              const float* __restrict__ src1, const float* __restrict__ st1,
              const float* __restrict__ src2, const float* __restrict__ st2,
              const float* __restrict__ W, const float* __restrict__ bias,
              float* __restrict__ Y, float* __restrict__ stout)
{
    __shared__ float XP[COUT][NN + (NN/32)*4];
    const int tid  = threadIdx.x;
    const int b    = blockIdx.x >> 5;
    const int tile = (blockIdx.x & 31) * 32;

    for (int k = tid; k < NN; k += 512) {
        float xw[COUT];
        if constexpr (CIN1 == 0) {
            const float4 v = *(const float4*)(xw1 + ((size_t)b*NN + k) * 4);
            xw[0]=v.x; xw[1]=v.y; xw[2]=v.z; xw[3]=v.w;
        } else {
            float in[CIN1 + CIN2];
            {
                const float cnt = 1.f / (32.f * CIN1);
                float m  = st1[k] * cnt;
                float ms = st1[NN + k] * cnt;
                float iv = rsqrtf(ms - m*m + 1e-5f);
                const float4 v = *(const float4*)(src1 + ((size_t)b*NN + k) * CIN1);
                in[0]=(v.x-m)*iv; in[1]=(v.y-m)*iv; in[2]=(v.z-m)*iv; in[3]=(v.w-m)*iv;
            }
            if constexpr (CIN2 > 0) {
                const float cnt = 1.f / (32.f * CIN2);
                float m  = st2[k] * cnt;
                float ms = st2[NN + k] * cnt;
                float iv = rsqrtf(ms - m*m + 1e-5f);
                const float2 v = *(const float2*)(src2 + ((size_t)b*NN + k) * CIN2);
                in[CIN1+0]=(v.x-m)*iv; in[CIN1+1]=(v.y-m)*iv;
            }
            #pragma unroll
            for (int c = 0; c < COUT; ++c) {
                float s = 0.f;
                #pragma unroll
                for (int i = 0; i < CIN1+CIN2; ++i) s += in[i]*W[i*COUT+c];
                xw[c] = s;
            }
        }
        const float dk = dd[(size_t)b*NN + k];
        const int mk = k + ((k >> 5) << 2);
        #pragma unroll
        for (int c = 0; c < COUT; ++c) XP[c][mk] = xw[c]*dk;
    }
    __syncthreads();

    const int lane = tid & 63, wid = tid >> 6;
    const int r0 = tile + wid * 4;
    float acc[4][COUT];
    #pragma unroll
    for (int j = 0; j < 4; ++j)
        #pragma unroll
        for (int c = 0; c < COUT; ++c) acc[j][c] = 0.f;
    float dn[4]; size_t rb[4];
    #pragma unroll
    for (int j = 0; j < 4; ++j) {
        dn[j] = dd[(size_t)b*NN + r0 + j];
        rb[j] = ((size_t)(b*NN + r0 + j)) * NN;
    }
    #pragma unroll
    for (int it = 0; it < 4; ++it) {
        const int kw = 4 * (lane + 64 * it);
        const int mb = kw + ((kw >> 5) << 2);
        float xwv[COUT][4];
        #pragma unroll
        for (int c = 0; c < COUT; ++c) {
            const float4 v = *(const float4*)&XP[c][mb];
            xwv[c][0]=v.x; xwv[c][1]=v.y; xwv[c][2]=v.z; xwv[c][3]=v.w;
        }
        #pragma unroll
        for (int j = 0; j < 4; ++j) {
            const int rr = r0 + j;
            float4 a = *(const float4*)(adj + rb[j] + kw);
            a.x = (kw + 0 == rr) ? 1.f : a.x;
            a.y = (kw + 1 == rr) ? 1.f : a.y;
            a.z = (kw + 2 == rr) ? 1.f : a.z;
            a.w = (kw + 3 == rr) ? 1.f : a.w;
            #pragma unroll
            for (int c = 0; c < COUT; ++c) {
                float s = acc[j][c];
                s = fmaf(a.x, xwv[c][0], s); s = fmaf(a.y, xwv[c][1], s);
                s = fmaf(a.z, xwv[c][2], s); s = fmaf(a.w, xwv[c][3], s);
                acc[j][c] = s;
            }
        }
    }
    #pragma unroll
    for (int j = 0; j < 4; ++j) {
        #pragma unroll
        for (int c = 0; c < COUT; ++c) {
            float v = acc[j][c];
            #pragma unroll
            for (int m = 1; m < 64; m <<= 1) v += __shfl_xor(v, m);
            acc[j][c] = v;
        }
        if (lane == 0) {
            float s = 0.f, q = 0.f;
            #pragma unroll
            for (int c = 0; c < COUT; ++c) {
                float y = acc[j][c] * dn[j] + bias[c];
                y = fmaxf(y, 0.f);
                Y[((size_t)(b*NN + r0 + j)) * COUT + c] = y;
                s += y; q += y * y;
            }
            atomicAdd(stout + (r0 + j), s);
            atomicAdd(stout + NN + (r0 + j), q);
        }
    }
}

// ------------------------------------------------------------------
// Final: 4 max-pools over nodes + linear [B,24]@[24,3]+bl
__global__ __launch_bounds__(256)
void k_final(const float* __restrict__ Y1, const float* __restrict__ Y2,
             const float* __restrict__ Y3, const float* __restrict__ Y4,
             const float* __restrict__ Y5, const float* __restrict__ Y6,
             const float* __restrict__ Y7, const float* __restrict__ Y8,
             const float* __restrict__ stats,
             const float* __restrict__ Wl, const float* __restrict__ bl,
             float* __restrict__ out)
{
    const float* Ya[4] = {Y1, Y3, Y5, Y7};
    const float* Yb[4] = {Y2, Y4, Y6, Y8};
    const int b = blockIdx.x, tid = threadIdx.x;
    float mx[24];
    #pragma unroll
    for (int i = 0; i < 24; ++i) mx[i] = -3.4e38f;

    for (int n = tid; n < NN; n += 256) {
        #pragma unroll
        for (int g = 0; g < 4; ++g) {
            {
                const float* st = stats + (size_t)(2*g) * 2048;
                const float cnt = 1.f / 128.f;
                float m  = st[n] * cnt;
                float ms = st[NN + n] * cnt;
                float iv = rsqrtf(ms - m*m + 1e-5f);
                const float4 v = *(const float4*)(Ya[g] + ((size_t)b*NN + n) * 4);
                mx[g*6+0] = fmaxf(mx[g*6+0], (v.x - m) * iv);
                mx[g*6+1] = fmaxf(mx[g*6+1], (v.y - m) * iv);
                mx[g*6+2] = fmaxf(mx[g*6+2], (v.z - m) * iv);
                mx[g*6+3] = fmaxf(mx[g*6+3], (v.w - m) * iv);
            }
            {
                const float* st = stats + (size_t)(2*g+1) * 2048;
                const float cnt = 1.f / 64.f;
                float m  = st[n] * cnt;
                float ms = st[NN + n] * cnt;
                float iv = rsqrtf(ms - m*m + 1e-5f);
                const float2 v = *(const float2*)(Yb[g] + ((size_t)b*NN + n) * 2);
                mx[g*6+4] = fmaxf(mx[g*6+4], (v.x - m) * iv);
                mx[g*6+5] = fmaxf(mx[g*6+5], (v.y - m) * iv);
            }
        }
    }
    const int lane = tid & 63, wid = tid >> 6;
    #pragma unroll
    for (int i = 0; i < 24; ++i) {
        float v = mx[i];
        #pragma unroll
        for (int m = 1; m < 64; m <<= 1) v = fmaxf(v, __shfl_xor(v, m));
        mx[i] = v;
    }
    __shared__ float red[4][24];
    __shared__ float pooled[24];
    if (lane == 0) {
        #pragma unroll
        for (int i = 0; i < 24; ++i) red[wid][i] = mx[i];
    }
    __syncthreads();
    if (tid < 24)
        pooled[tid] = fmaxf(fmaxf(red[0][tid], red[1][tid]),
                            fmaxf(red[2][tid], red[3][tid]));
    __syncthreads();
    if (tid < 3) {
        float s = bl[tid];
        #pragma unroll
        for (int c = 0; c < 24; ++c) s += pooled[c] * Wl[c*3 + tid];
        out[b*3 + tid] = s;
    }
}

// ------------------------------------------------------------------
extern "C" void kernel_launch(void* const* d_in, const int* in_sizes, int n_in,
                              void* d_out, int out_size, void* d_ws, size_t ws_size,
                              hipStream_t stream)
{
    const float* x   = (const float*)d_in[0];
    const float* adj = (const float*)d_in[1];
    const float* W1  = (const float*)d_in[2];
    const float* b1  = (const float*)d_in[3];
    const float* W2  = (const float*)d_in[4];
    const float* b2  = (const float*)d_in[5];
    const float* W3  = (const float*)d_in[6];
    const float* b3  = (const float*)d_in[7];
    const float* W5  = (const float*)d_in[8];
    const float* b5  = (const float*)d_in[9];
    const float* W7  = (const float*)d_in[10];
    const float* b7  = (const float*)d_in[11];
    const float* Wl  = (const float*)d_in[12];
    const float* bl  = (const float*)d_in[13];
    float* out = (float*)d_out;

    float* wsf   = (float*)d_ws;
    float* dd    = wsf + F_D;
    float* stats = wsf + F_STATS;
    float* xw1   = wsf + F_XW1;
    float* Y[8];
    #pragma unroll
    for (int i = 0; i < 8; ++i) Y[i] = wsf + F_Y[i];
    __half* ah = (__half*)((char*)d_ws + AH_BYTE_OFF);
    const bool use_half = (ws_size >= WS_NEED_HALF);

    k0_prep<<<8384, 256, 0, stream>>>(adj, x, W1, dd, xw1, stats,
                                      use_half ? ah : nullptr);

    #define STT(i) (stats + (i)*2048)
    if (use_half) {
        const dim3 pg(1024), pb(512);
        pass_half<0,0,4><<<pg, pb, 0, stream>>>(ah, dd, xw1,
            nullptr, nullptr, nullptr, nullptr, nullptr, b1, Y[0], STT(0));
        pass_half<4,0,2><<<pg, pb, 0, stream>>>(ah, dd, nullptr,
            Y[0], STT(0), nullptr, nullptr, W2, b2, Y[1], STT(1));
        pass_half<4,2,4><<<pg, pb, 0, stream>>>(ah, dd, nullptr,
            Y[0], STT(0), Y[1], STT(1), W3, b3, Y[2], STT(2));
        pass_half<4,0,2><<<pg, pb, 0, stream>>>(ah, dd, nullptr,
            Y[2], STT(2), nullptr, nullptr, W2, b2, Y[3], STT(3));
        pass_half<4,2,4><<<pg, pb, 0, stream>>>(ah, dd, nullptr,
            Y[2], STT(2), Y[3], STT(3), W5, b5, Y[4], STT(4));
        pass_half<4,0,2><<<pg, pb, 0, stream>>>(ah, dd, nullptr,
            Y[4], STT(4), nullptr, nullptr, W2, b2, Y[5], STT(5));
        pass_half<4,2,4><<<pg, pb, 0, stream>>>(ah, dd, nullptr,
            Y[4], STT(4), Y[5], STT(5), W7, b7, Y[6], STT(6));
        pass_half<4,0,2><<<pg, pb, 0, stream>>>(ah, dd, nullptr,
            Y[6], STT(6), nullptr, nullptr, W2, b2, Y[7], STT(7));
    } else {
        const dim3 pg(1024), pb(512);
        pass_f32<0,0,4><<<pg, pb, 0, stream>>>(adj, dd, xw1,
            nullptr, nullptr, nullptr, nullptr, nullptr, b1, Y[0], STT(0));
        pass_f32<4,0,2><<<pg, pb, 0, stream>>>(adj, dd, nullptr,
            Y[0], STT(0), nullptr, nullptr, W2, b2, Y[1], STT(1));
        pass_f32<4,2,4><<<pg, pb, 0, stream>>>(adj, dd, nullptr,
            Y[0], STT(0), Y[1], STT(1), W3, b3, Y[2], STT(2));
        pass_f32<4,0,2><<<pg, pb, 0, stream>>>(adj, dd, nullptr,
            Y[2], STT(2), nullptr, nullptr, W2, b2, Y[3], STT(3));
        pass_f32<4,2,4><<<pg, pb, 0, stream>>>(adj, dd, nullptr,
            Y[2], STT(2), Y[3], STT(3), W5, b5, Y[4], STT(4));
        pass_f32<4,0,2><<<pg, pb, 0, stream>>>(adj, dd, nullptr,
            Y[4], STT(4), nullptr, nullptr, W2, b2, Y[5], STT(5));
        pass_f32<4,2,4><<<pg, pb, 0, stream>>>(adj, dd, nullptr,
            Y[4], STT(4), Y[5], STT(5), W7, b7, Y[6], STT(6));
        pass_f32<4,0,2><<<pg, pb, 0, stream>>>(adj, dd, nullptr,
            Y[6], STT(6), nullptr, nullptr, W2, b2, Y[7], STT(7));
    }
    #undef STT

    k_final<<<32, 256, 0, stream>>>(Y[0], Y[1], Y[2], Y[3], Y[4], Y[5], Y[6], Y[7],
                                    stats, Wl, bl, out);
}

// Round 11
// 155.621 us; speedup vs baseline: 1.4783x; 1.4783x over previous
//
#include <hip/hip_runtime.h>
#include <hip/hip_fp16.h>

#define NB 32
#define NN 1024

typedef _Float16 h2 __attribute__((ext_vector_type(2)));
typedef _Float16 h8 __attribute__((ext_vector_type(8)));

// ---------------- ws layout (floats unless noted) ----------------
static const size_t F_D     = 0;        // 32768  : rsqrt degree [B,N]
static const size_t F_STATS = 32768;    // 16384  : 8 x {sum[1024], sumsq[1024]}
static const size_t F_XW1   = 49152;    // 131072 : x @ W1  [B,N,4]
static constexpr size_t F_Y[8] = {180224, 311296, 376832, 507904,
                                  573440, 704512, 770048, 901120};
static const size_t AH_BYTE_OFF  = 3866624;                 // fp16 adj(diag=1), 64MB
static const size_t WS_NEED_HALF = AH_BYTE_OFF + (size_t)NB*NN*NN*2;

__device__ __forceinline__ float fdot2f(h2 a, h2 b, float c) {
#if __has_builtin(__builtin_amdgcn_fdot2)
    return __builtin_amdgcn_fdot2(a, b, c, false);
#else
    return c + (float)a[0]*(float)b[0] + (float)a[1]*(float)b[1];
#endif
}

// ------------------------------------------------------------------
// K0: degree + write fp16 ah(diag=1) + XW1 precompute + stats zero
__global__ __launch_bounds__(256)
void k0_prep(const float* __restrict__ adj, const float* __restrict__ x,
             const float* __restrict__ W1, float* __restrict__ dd,
             float* __restrict__ xw1, float* __restrict__ stats,
             __half* __restrict__ ahw)
{
    const int tid = threadIdx.x;
    const int bx  = blockIdx.x;
    if (bx < 8192) {
        const int lane = tid & 63, wid = tid >> 6;
        const int row = bx * 4 + wid;          // b*1024+n
        const int n = row & (NN - 1);
        const float4* arow = (const float4*)(adj + (size_t)row * NN);
        uint2* hrow = (uint2*)(ahw + (size_t)row * NN);
        float s = 0.f;
        #pragma unroll
        for (int it = 0; it < 4; ++it) {
            const int idx = lane + it * 64;
            float4 v = arow[idx];
            const int k0 = idx * 4;
            v.x = (k0 + 0 == n) ? 1.f : v.x;
            v.y = (k0 + 1 == n) ? 1.f : v.y;
            v.z = (k0 + 2 == n) ? 1.f : v.z;
            v.w = (k0 + 3 == n) ? 1.f : v.w;
            s += v.x + v.y + v.z + v.w;
            if (ahw) {
                __half2 h01 = __floats2half2_rn(v.x, v.y);
                __half2 h23 = __floats2half2_rn(v.z, v.w);
                uint2 u;
                u.x = *(unsigned*)&h01; u.y = *(unsigned*)&h23;
                hrow[idx] = u;
            }
        }
        #pragma unroll
        for (int m = 1; m < 64; m <<= 1) s += __shfl_xor(s, m);
        if (lane == 0) dd[row] = rsqrtf(fmaxf(s, 1.f));
    } else if (bx < 8320) {
        const int id = (bx - 8192) * 256 + tid;   // b*1024+k
        const float4* xr = (const float4*)(x + (size_t)id * 32);
        float in[32];
        #pragma unroll
        for (int i = 0; i < 8; ++i) {
            float4 v = xr[i];
            in[4*i]=v.x; in[4*i+1]=v.y; in[4*i+2]=v.z; in[4*i+3]=v.w;
        }
        float o[4] = {0.f,0.f,0.f,0.f};
        #pragma unroll
        for (int i = 0; i < 32; ++i)
            #pragma unroll
            for (int c = 0; c < 4; ++c) o[c] += in[i] * W1[i*4+c];
        *(float4*)(xw1 + (size_t)id * 4) = make_float4(o[0],o[1],o[2],o[3]);
    } else {
        const int id = (bx - 8320) * 256 + tid;   // < 16384
        stats[id] = 0.f;
    }
}

// ------------------------------------------------------------------
// Stage one 128-half (256B/row) chunk of this wave's 8 rows into its own
// 2KB region of a 16KB chunk buffer. Linear LDS dest; source pre-swizzled
// col ^= (row&7)<<4 so swizzled reads are bank-floor. 2 loads/chunk/wave.
__device__ __forceinline__ void stage16(const __half* __restrict__ ah,
        int rowbase, int wid, int lane, int ck, char* sbuf)
{
    #pragma unroll
    for (int i = 0; i < 2; ++i) {
        const int ob = (wid << 11) + (i << 10);
        const int o  = ob + (lane << 4);
        const int row = o >> 8;                       // tile row 0..63
        const int scol = (o & 255) ^ ((row & 7) << 4);
        const char* g = (const char*)ah +
            (((size_t)(rowbase + row)) * NN + (size_t)ck * 128) * 2 + scol;
#if __has_builtin(__builtin_amdgcn_global_load_lds)
        __builtin_amdgcn_global_load_lds(
            (const __attribute__((address_space(1))) void*)g,
            (__attribute__((address_space(3))) void*)(sbuf + ob),
            16, 0, 0);
#else
        *(float4*)(sbuf + o) = *(const float4*)g;
#endif
    }
}

// ------------------------------------------------------------------
// Pass kernel: Y = relu(Anorm @ XW + b), Anorm = d[r]*ah[r][k]*d[k].
// Grid 512: b = bid>>4, tile = (bid&15)*64. 8 waves x 8 rows.
// Thread (wid, rp=lane>>4, ll=lane&15) jams 2 rows (tr0=wid*8+rp*2) and owns
// k-slice ll*8..+8 of each 128-half chunk. Per-wave autonomous pipeline:
// counted vmcnt(2) (never 0 mid-loop), lgkmcnt(0)-only before buffer reuse,
// NO per-chunk block barriers. One barrier total (XPc publish).
template<int CIN1, int CIN2, int COUT>
__global__ __launch_bounds__(512, 6)
void pass_half(const __half* __restrict__ ah, const float* __restrict__ dd,
               const float* __restrict__ xw1,
               const float* __restrict__ src1, const float* __restrict__ st1,
               const float* __restrict__ src2, const float* __restrict__ st2,
               const float* __restrict__ W, const float* __restrict__ bias,
               float* __restrict__ Y, float* __restrict__ stout)
{
    __shared__ char sA[2][16384];              // 2 x (64 rows x 256B)
    __shared__ _Float16 XPc[COUT][NN];         // per-channel XW*dk (linear)
    const int tid = threadIdx.x, lane = tid & 63, wid = tid >> 6;
    const int rp = lane >> 4, ll = lane & 15;
    const int b = blockIdx.x >> 4;
    const int tile = (blockIdx.x & 15) << 6;
    const int rowbase = b * NN + tile;

    // issue first two chunk stages (4 loads/wave in flight)
    stage16(ah, rowbase, wid, lane, 0, sA[0]);
    stage16(ah, rowbase, wid, lane, 1, sA[1]);

    // ---- prologue: build fp16 XW (d[k] folded); 2 k per thread ----
    {
        const int k0 = tid * 2;
        float xwa[COUT], xwb[COUT];
        if constexpr (CIN1 == 0) {
            const float4 va = *(const float4*)(xw1 + ((size_t)b*NN + k0) * 4);
            const float4 vb = *(const float4*)(xw1 + ((size_t)b*NN + k0 + 1) * 4);
            xwa[0]=va.x; xwa[1]=va.y; xwa[2]=va.z; xwa[3]=va.w;
            xwb[0]=vb.x; xwb[1]=vb.y; xwb[2]=vb.z; xwb[3]=vb.w;
        } else {
            float ina[CIN1 + CIN2], inb[CIN1 + CIN2];
            {
                const float cnt = 1.f / (32.f * CIN1);
                #pragma unroll
                for (int t = 0; t < 2; ++t) {
                    const int k = k0 + t;
                    float* in = t ? inb : ina;
                    const float m  = st1[k] * cnt;
                    const float ms = st1[NN + k] * cnt;
                    const float iv = rsqrtf(ms - m*m + 1e-5f);
                    const float4 v = *(const float4*)(src1 + ((size_t)b*NN + k) * CIN1);
                    in[0]=(v.x-m)*iv; in[1]=(v.y-m)*iv; in[2]=(v.z-m)*iv; in[3]=(v.w-m)*iv;
                }
            }
            if constexpr (CIN2 > 0) {
                const float cnt = 1.f / (32.f * CIN2);
                #pragma unroll
                for (int t = 0; t < 2; ++t) {
                    const int k = k0 + t;
                    float* in = t ? inb : ina;
                    const float m  = st2[k] * cnt;
                    const float ms = st2[NN + k] * cnt;
                    const float iv = rsqrtf(ms - m*m + 1e-5f);
                    const float2 v = *(const float2*)(src2 + ((size_t)b*NN + k) * CIN2);
                    in[CIN1+0]=(v.x-m)*iv; in[CIN1+1]=(v.y-m)*iv;
                }
            }
            #pragma unroll
            for (int c = 0; c < COUT; ++c) {
                float sa = 0.f, sb = 0.f;
                #pragma unroll
                for (int i = 0; i < CIN1+CIN2; ++i) {
                    sa += ina[i]*W[i*COUT+c];
                    sb += inb[i]*W[i*COUT+c];
                }
                xwa[c] = sa; xwb[c] = sb;
            }
        }
        const float dka = dd[b*NN + k0];
        const float dkb = dd[b*NN + k0 + 1];
        #pragma unroll
        for (int c = 0; c < COUT; ++c) {
            h2 v; v[0] = (_Float16)(xwa[c]*dka); v[1] = (_Float16)(xwb[c]*dkb);
            *(h2*)&XPc[c][k0] = v;
        }
    }
    // publish XPc without draining the stage loads
    asm volatile("s_waitcnt lgkmcnt(0)" ::: "memory");
    __builtin_amdgcn_s_barrier();
    __builtin_amdgcn_sched_barrier(0);

    // ---- wave-autonomous chunk loop (8 chunks, counted vmcnt) ----
    const int tr0 = wid*8 + rp*2;
    float acc[2][COUT];
    #pragma unroll
    for (int j = 0; j < 2; ++j)
        #pragma unroll
        for (int c = 0; c < COUT; ++c) acc[j][c] = 0.f;

    #pragma unroll
    for (int ck = 0; ck < 8; ++ck) {
        if (ck == 7) asm volatile("s_waitcnt vmcnt(0)" ::: "memory");
        else         asm volatile("s_waitcnt vmcnt(2)" ::: "memory");
        // XW fragment (shared by both jammed rows)
        h8 xt[COUT];
        #pragma unroll
        for (int c = 0; c < COUT; ++c)
            xt[c] = *(const h8*)&XPc[c][ck*128 + ll*8];
        const char* buf = sA[ck & 1];
        #pragma unroll
        for (int j = 0; j < 2; ++j) {
            const int tr = tr0 + j;
            const h8 av = *(const h8*)(buf + tr*256 + ((ll ^ (tr & 7)) << 4));
            const h2* a2 = (const h2*)&av;
            #pragma unroll
            for (int c = 0; c < COUT; ++c) {
                const h2* x2 = (const h2*)&xt[c];
                float s = acc[j][c];
                #pragma unroll
                for (int p = 0; p < 4; ++p)
                    s = fdot2f(a2[p], x2[p], s);
                acc[j][c] = s;
            }
        }
        if (ck < 6) {
            // own ds_reads done before overwriting this buffer (wave-local)
            asm volatile("s_waitcnt lgkmcnt(0)" ::: "memory");
            stage16(ah, rowbase, wid, lane, ck + 2, sA[ck & 1]);
        }
    }

    // ---- reduce over ll (16 lanes), epilogue ----
    #pragma unroll
    for (int j = 0; j < 2; ++j)
        #pragma unroll
        for (int c = 0; c < COUT; ++c) {
            float v = acc[j][c];
            v += __shfl_xor(v, 1);  v += __shfl_xor(v, 2);
            v += __shfl_xor(v, 4);  v += __shfl_xor(v, 8);
            acc[j][c] = v;
        }
    if (ll == 0) {
        #pragma unroll
        for (int j = 0; j < 2; ++j) {
            const int n = tile + tr0 + j;
            const float dn = dd[b*NN + n];
            float s = 0.f, q2 = 0.f;
            float y[COUT];
            #pragma unroll
            for (int c = 0; c < COUT; ++c) {
                float t = acc[j][c] * dn + bias[c];
                t = fmaxf(t, 0.f);
                y[c] = t; s += t; q2 += t*t;
            }
            if constexpr (COUT == 4)
                *(float4*)(Y + ((size_t)(b*NN + n))*4) = make_float4(y[0],y[1],y[2],y[3]);
            else
                *(float2*)(Y + ((size_t)(b*NN + n))*2) = make_float2(y[0],y[1]);
            atomicAdd(stout + n, s);
            atomicAdd(stout + NN + n, q2);
        }
    }
}

// ------------------------------------------------------------------
// Fallback fp32 pass (no ah): direct adj reads (R2-proven path).
template<int CIN1, int CIN2, int COUT>
__global__ __launch_bounds__(512)
void pass_f32(const float* __restrict__ adj, const float* __restrict__ dd,
              const float* __restrict__ xw1,
              const float* __restrict__ src1, const float* __restrict__ st1,
              const float* __restrict__ src2, const float* __restrict__ st2,
              const float* __restrict__ W, const float* __restrict__ bias,
              float* __restrict__ Y, float* __restrict__ stout)
{
    __shared__ float XP[COUT][NN + (NN/32)*4];
    const int tid  = threadIdx.x;
    const int b    = blockIdx.x >> 5;
    const int tile = (blockIdx.x & 31) * 32;

    for (int k = tid; k < NN; k += 512) {
        float xw[COUT];
        if constexpr (CIN1 == 0) {
            const float4 v = *(const float4*)(xw1 + ((size_t)b*NN + k) * 4);
            xw[0]=v.x; xw[1]=v.y; xw[2]=v.z; xw[3]=v.w;
        } else {
            float in[CIN1 + CIN2];
            {
                const float cnt = 1.f / (32.f * CIN1);
                float m  = st1[k] * cnt;
                float ms = st1[NN + k] * cnt;
                float iv = rsqrtf(ms - m*m + 1e-5f);
                const float4 v = *(const float4*)(src1 + ((size_t)b*NN + k) * CIN1);
                in[0]=(v.x-m)*iv; in[1]=(v.y-m)*iv; in[2]=(v.z-m)*iv; in[3]=(v.w-m)*iv;
            }
            if constexpr (CIN2 > 0) {
                const float cnt = 1.f / (32.f * CIN2);
                float m  = st2[k] * cnt;
                float ms = st2[NN + k] * cnt;
                float iv = rsqrtf(ms - m*m + 1e-5f);
                const float2 v = *(const float2*)(src2 + ((size_t)b*NN + k) * CIN2);
                in[CIN1+0]=(v.x-m)*iv; in[CIN1+1]=(v.y-m)*iv;
            }
            #pragma unroll
            for (int c = 0; c < COUT; ++c) {
                float s = 0.f;
                #pragma unroll
                for (int i = 0; i < CIN1+CIN2; ++i) s += in[i]*W[i*COUT+c];
                xw[c] = s;
            }
        }
        const float dk = dd[(size_t)b*NN + k];
        const int mk = k + ((k >> 5) << 2);
        #pragma unroll
        for (int c = 0; c < COUT; ++c) XP[c][mk] = xw[c]*dk;
    }
    __syncthreads();

    const int lane = tid & 63, wid = tid >> 6;
    const int r0 = tile + wid * 4;
    float acc[4][COUT];
    #pragma unroll
    for (int j = 0; j < 4; ++j)
        #pragma unroll
        for (int c = 0; c < COUT; ++c) acc[j][c] = 0.f;
    float dn[4]; size_t rb[4];
    #pragma unroll
    for (int j = 0; j < 4; ++j) {
        dn[j] = dd[(size_t)b*NN + r0 + j];
        rb[j] = ((size_t)(b*NN + r0 + j)) * NN;
    }
    #pragma unroll
    for (int it = 0; it < 4; ++it) {
        const int kw = 4 * (lane + 64 * it);
        const int mb = kw + ((kw >> 5) << 2);
        float xwv[COUT][4];
        #pragma unroll
        for (int c = 0; c < COUT; ++c) {
            const float4 v = *(const float4*)&XP[c][mb];
            xwv[c][0]=v.x; xwv[c][1]=v.y; xwv[c][2]=v.z; xwv[c][3]=v.w;
        }
        #pragma unroll
        for (int j = 0; j < 4; ++j) {
            const int rr = r0 + j;
            float4 a = *(const float4*)(adj + rb[j] + kw);
            a.x = (kw + 0 == rr) ? 1.f : a.x;
            a.y = (kw + 1 == rr) ? 1.f : a.y;
            a.z = (kw + 2 == rr) ? 1.f : a.z;
            a.w = (kw + 3 == rr) ? 1.f : a.w;
            #pragma unroll
            for (int c = 0; c < COUT; ++c) {
                float s = acc[j][c];
                s = fmaf(a.x, xwv[c][0], s); s = fmaf(a.y, xwv[c][1], s);
                s = fmaf(a.z, xwv[c][2], s); s = fmaf(a.w, xwv[c][3], s);
                acc[j][c] = s;
            }
        }
    }
    #pragma unroll
    for (int j = 0; j < 4; ++j) {
        #pragma unroll
        for (int c = 0; c < COUT; ++c) {
            float v = acc[j][c];
            #pragma unroll
            for (int m = 1; m < 64; m <<= 1) v += __shfl_xor(v, m);
            acc[j][c] = v;
        }
        if (lane == 0) {
            float s = 0.f, q = 0.f;
            #pragma unroll
            for (int c = 0; c < COUT; ++c) {
                float y = acc[j][c] * dn[j] + bias[c];
                y = fmaxf(y, 0.f);
                Y[((size_t)(b*NN + r0 + j)) * COUT + c] = y;
                s += y; q += y * y;
            }
            atomicAdd(stout + (r0 + j), s);
            atomicAdd(stout + NN + (r0 + j), q);
        }
    }
}

// ------------------------------------------------------------------
// Final: 4 max-pools over nodes + linear [B,24]@[24,3]+bl
__global__ __launch_bounds__(256)
void k_final(const float* __restrict__ Y1, const float* __restrict__ Y2,
             const float* __restrict__ Y3, const float* __restrict__ Y4,
             const float* __restrict__ Y5, const float* __restrict__ Y6,
             const float* __restrict__ Y7, const float* __restrict__ Y8,
             const float* __restrict__ stats,
             const float* __restrict__ Wl, const float* __restrict__ bl,
             float* __restrict__ out)
{
    const float* Ya[4] = {Y1, Y3, Y5, Y7};
    const float* Yb[4] = {Y2, Y4, Y6, Y8};
    const int b = blockIdx.x, tid = threadIdx.x;
    float mx[24];
    #pragma unroll
    for (int i = 0; i < 24; ++i) mx[i] = -3.4e38f;

    for (int n = tid; n < NN; n += 256) {
        #pragma unroll
        for (int g = 0; g < 4; ++g) {
            {
                const float* st = stats + (size_t)(2*g) * 2048;
                const float cnt = 1.f / 128.f;
                float m  = st[n] * cnt;
                float ms = st[NN + n] * cnt;
                float iv = rsqrtf(ms - m*m + 1e-5f);
                const float4 v = *(const float4*)(Ya[g] + ((size_t)b*NN + n) * 4);
                mx[g*6+0] = fmaxf(mx[g*6+0], (v.x - m) * iv);
                mx[g*6+1] = fmaxf(mx[g*6+1], (v.y - m) * iv);
                mx[g*6+2] = fmaxf(mx[g*6+2], (v.z - m) * iv);
                mx[g*6+3] = fmaxf(mx[g*6+3], (v.w - m) * iv);
            }
            {
                const float* st = stats + (size_t)(2*g+1) * 2048;
                const float cnt = 1.f / 64.f;
                float m  = st[n] * cnt;
                float ms = st[NN + n] * cnt;
                float iv = rsqrtf(ms - m*m + 1e-5f);
                const float2 v = *(const float2*)(Yb[g] + ((size_t)b*NN + n) * 2);
                mx[g*6+4] = fmaxf(mx[g*6+4], (v.x - m) * iv);
                mx[g*6+5] = fmaxf(mx[g*6+5], (v.y - m) * iv);
            }
        }
    }
    const int lane = tid & 63, wid = tid >> 6;
    #pragma unroll
    for (int i = 0; i < 24; ++i) {
        float v = mx[i];
        #pragma unroll
        for (int m = 1; m < 64; m <<= 1) v = fmaxf(v, __shfl_xor(v, m));
        mx[i] = v;
    }
    __shared__ float red[4][24];
    __shared__ float pooled[24];
    if (lane == 0) {
        #pragma unroll
        for (int i = 0; i < 24; ++i) red[wid][i] = mx[i];
    }
    __syncthreads();
    if (tid < 24)
        pooled[tid] = fmaxf(fmaxf(red[0][tid], red[1][tid]),
                            fmaxf(red[2][tid], red[3][tid]));
    __syncthreads();
    if (tid < 3) {
        float s = bl[tid];
        #pragma unroll
        for (int c = 0; c < 24; ++c) s += pooled[c] * Wl[c*3 + tid];
        out[b*3 + tid] = s;
    }
}

// ------------------------------------------------------------------
extern "C" void kernel_launch(void* const* d_in, const int* in_sizes, int n_in,
                              void* d_out, int out_size, void* d_ws, size_t ws_size,
                              hipStream_t stream)
{
    const float* x   = (const float*)d_in[0];
    const float* adj = (const float*)d_in[1];
    const float* W1  = (const float*)d_in[2];
    const float* b1  = (const float*)d_in[3];
    const float* W2  = (const float*)d_in[4];
    const float* b2  = (const float*)d_in[5];
    const float* W3  = (const float*)d_in[6];
    const float* b3  = (const float*)d_in[7];
    const float* W5  = (const float*)d_in[8];
    const float* b5  = (const float*)d_in[9];
    const float* W7  = (const float*)d_in[10];
    const float* b7  = (const float*)d_in[11];
    const float* Wl  = (const float*)d_in[12];
    const float* bl  = (const float*)d_in[13];
    float* out = (float*)d_out;

    float* wsf   = (float*)d_ws;
    float* dd    = wsf + F_D;
    float* stats = wsf + F_STATS;
    float* xw1   = wsf + F_XW1;
    float* Y[8];
    #pragma unroll
    for (int i = 0; i < 8; ++i) Y[i] = wsf + F_Y[i];
    __half* ah = (__half*)((char*)d_ws + AH_BYTE_OFF);
    const bool use_half = (ws_size >= WS_NEED_HALF);

    k0_prep<<<8384, 256, 0, stream>>>(adj, x, W1, dd, xw1, stats,
                                      use_half ? ah : nullptr);

    #define STT(i) (stats + (i)*2048)
    if (use_half) {
        const dim3 pg(512), pb(512);
        pass_half<0,0,4><<<pg, pb, 0, stream>>>(ah, dd, xw1,
            nullptr, nullptr, nullptr, nullptr, nullptr, b1, Y[0], STT(0));
        pass_half<4,0,2><<<pg, pb, 0, stream>>>(ah, dd, nullptr,
            Y[0], STT(0), nullptr, nullptr, W2, b2, Y[1], STT(1));
        pass_half<4,2,4><<<pg, pb, 0, stream>>>(ah, dd, nullptr,
            Y[0], STT(0), Y[1], STT(1), W3, b3, Y[2], STT(2));
        pass_half<4,0,2><<<pg, pb, 0, stream>>>(ah, dd, nullptr,
            Y[2], STT(2), nullptr, nullptr, W2, b2, Y[3], STT(3));
        pass_half<4,2,4><<<pg, pb, 0, stream>>>(ah, dd, nullptr,
            Y[2], STT(2), Y[3], STT(3), W5, b5, Y[4], STT(4));
        pass_half<4,0,2><<<pg, pb, 0, stream>>>(ah, dd, nullptr,
            Y[4], STT(4), nullptr, nullptr, W2, b2, Y[5], STT(5));
        pass_half<4,2,4><<<pg, pb, 0, stream>>>(ah, dd, nullptr,
            Y[4], STT(4), Y[5], STT(5), W7, b7, Y[6], STT(6));
        pass_half<4,0,2><<<pg, pb, 0, stream>>>(ah, dd, nullptr,
            Y[6], STT(6), nullptr, nullptr, W2, b2, Y[7], STT(7));
    } else {
        const dim3 pg(1024), pb(512);
        pass_f32<0,0,4><<<pg, pb, 0, stream>>>(adj, dd, xw1,
            nullptr, nullptr, nullptr, nullptr, nullptr, b1, Y[0], STT(0));
        pass_f32<4,0,2><<<pg, pb, 0, stream>>>(adj, dd, nullptr,
            Y[0], STT(0), nullptr, nullptr, W2, b2, Y[1], STT(1));
        pass_f32<4,2,4><<<pg, pb, 0, stream>>>(adj, dd, nullptr,
            Y[0], STT(0), Y[1], STT(1), W3, b3, Y[2], STT(2));
        pass_f32<4,0,2><<<pg, pb, 0, stream>>>(adj, dd, nullptr,
            Y[2], STT(2), nullptr, nullptr, W2, b2, Y[3], STT(3));
        pass_f32<4,2,4><<<pg, pb, 0, stream>>>(adj, dd, nullptr,
            Y[2], STT(2), Y[3], STT(3), W5, b5, Y[4], STT(4));
        pass_f32<4,0,2><<<pg, pb, 0, stream>>>(adj, dd, nullptr,
            Y[4], STT(4), nullptr, nullptr, W2, b2, Y[5], STT(5));
        pass_f32<4,2,4><<<pg, pb, 0, stream>>>(adj, dd, nullptr,
            Y[4], STT(4), Y[5], STT(5), W7, b7, Y[6], STT(6));
        pass_f32<4,0,2><<<pg, pb, 0, stream>>>(adj, dd, nullptr,
            Y[6], STT(6), nullptr, nullptr, W2, b2, Y[7], STT(7));
    }
    #undef STT

    k_final<<<32, 256, 0, stream>>>(Y[0], Y[1], Y[2], Y[3], Y[4], Y[5], Y[6], Y[7],
                                    stats, Wl, bl, out);
}